// Round 16
// baseline (192.863 us; speedup 1.0000x reference)
//
#include <hip/hip_runtime.h>

#define N  192
#define N2 (N * N)
#define N3 (N * N * N)

// Block: 32x8 (x,y) tile marching ZC planes in z, TWO planes per iteration.
// R16: halves per-plane barrier/chain overhead (2 lgkm barriers per 2 planes)
// and doubles compute-phase ILP (two independent flux evals). LDS 41.5 KB ->
// 3 blocks/CU (12 waves) — measured cost of that is only ~3% (R7 vs R8).
#define TX 32
#define TY 8
#define NT 256
#define ZC 12
#define NIT (ZC / 2)          // 6 double-plane iterations
#define GX (N / TX)           // 6
#define GY (N / TY)           // 24
#define GZ (N / ZC)           // 16
#define NBLK (GX * GY * GZ)   // 2304 (divisible by 8 XCDs)
#define UX (TX + 4)           // 36  (u/T halo +-2)
#define UY (TY + 4)           // 12
#define UP (UX * UY)          // 432
#define FX (TX + 2)           // 34  (flux halo +-1)
#define FY (TY + 2)           // 10
#define FP (FX * FY)          // 340

static constexpr float INV2DX     = (float)N / 2.0f;   // 96
static constexpr float SCALE2     = INV2DX * INV2DX;   // 9216 (exact)
static constexpr float MU_REF_F   = 1.8e-5f;
static constexpr float CP_OVER_PR = 1005.0f / 0.72f;
static constexpr float TWO_THIRDS = 2.0f / 3.0f;

__device__ __forceinline__ int wrapN(int a) {  // valid for a in [-N, 2N)
    if (a < 0)  a += N;
    if (a >= N) a -= N;
    return a;
}

struct Flux { float t00, t01, t02, t11, t12, t22, F0, F1, F2; };

// Fully register-fed flux eval: own column {zm,cc,zp} + 4 xy-neighbors.
// No 1/(2dx) factor — single INV2DX^2 applied at the output store.
__device__ __forceinline__ Flux flux_eval(const float4 zm, const float4 cc,
                                          const float4 zp,
                                          const float4 xp, const float4 xm,
                                          const float4 yp, const float4 ym)
{
    const float d00 = zp.x - zm.x;
    const float d01 = yp.x - ym.x;
    const float d02 = xp.x - xm.x;
    const float d10 = zp.y - zm.y;
    const float d11 = yp.y - ym.y;
    const float d12 = xp.y - xm.y;
    const float d20 = zp.z - zm.z;
    const float d21 = yp.z - ym.z;
    const float d22 = xp.z - xm.z;
    const float dT0 = zp.w - zm.w;
    const float dT1 = yp.w - ym.w;
    const float dT2 = xp.w - xm.w;

    const float mu   = MU_REF_F * __powf(cc.w, 0.7f);
    const float mu2  = mu + mu;
    const float divu = d00 + d11 + d22;
    const float lam  = -TWO_THIRDS * mu * divu;

    Flux f;
    f.t00 = mu2 * d00 + lam;
    f.t11 = mu2 * d11 + lam;
    f.t22 = mu2 * d22 + lam;
    f.t01 = mu * (d01 + d10);
    f.t02 = mu * (d02 + d20);
    f.t12 = mu * (d12 + d21);
    const float kc = mu * CP_OVER_PR;
    f.F0 = kc * dT0 + f.t00 * cc.x + f.t01 * cc.y + f.t02 * cc.z;
    f.F1 = kc * dT1 + f.t01 * cc.x + f.t11 * cc.y + f.t12 * cc.z;
    f.F2 = kc * dT2 + f.t02 * cc.x + f.t12 * cc.y + f.t22 * cc.z;
    return f;
}

// Prologue-only: whole stencil from LDS.
__device__ __forceinline__ Flux flux_eval_at(const float4* __restrict__ uM,
                                             const float4* __restrict__ uC,
                                             const float4* __restrict__ uP, int c)
{
    return flux_eval(uM[c], uC[c], uP[c], uC[c + 1], uC[c - 1],
                     uC[c + UX], uC[c - UX]);
}

__global__ __launch_bounds__(NT, 3)
void diffusion_zmarch2_kernel(const float* __restrict__ u,
                              const float* __restrict__ Tp,
                              float* __restrict__ out)
{
    __shared__ float4 su4[3][UP];            // 3 rolling u/T planes (20.25 KB)
    __shared__ float4 sfAY[FP], sfAX[FP];    // even-plane flux fields (10.6 KB)
    __shared__ float4 sfBY[FP], sfBX[FP];    // odd-plane  flux fields (10.6 KB)
    // total 41.5 KB -> 3 blocks/CU

    // ---- bijective XCD swizzle on the flat block id (NBLK % 8 == 0) ----
    const int id  = (int)blockIdx.x;
    const int nid = (id & 7) * (NBLK / 8) + (id >> 3);
    const int bzB = nid / (GX * GY);
    const int rem = nid % (GX * GY);
    const int bx  = (rem % GX) * TX;
    const int by  = (rem / GX) * TY;
    const int z0  = bzB * ZC;

    const int tx  = threadIdx.x & (TX - 1);
    const int ty  = threadIdx.x >> 5;
    const int tid = (int)threadIdx.x;

    const float* __restrict__ u0 = u;
    const float* __restrict__ u1 = u + N3;
    const float* __restrict__ u2 = u + 2 * N3;

    const int cu = (ty + 2) * UX + (tx + 2);   // interior u-site
    const int fi = (ty + 1) * FX + (tx + 1);   // interior flux-site

    // halo flux site for tid < 80 (corners excluded — never read)
    int hfx = -1, hfy = -1;
    if (tid < TX)                 { hfy = 0;      hfx = 1 + tid; }
    else if (tid < 2 * TX)        { hfy = FY - 1; hfx = 1 + tid - TX; }
    else if (tid < 2 * TX + TY)   { hfx = 0;      hfy = 1 + tid - 2 * TX; }
    else if (tid < 2 * (TX + TY)) { hfx = FX - 1; hfy = 1 + tid - 2 * TX - TY; }
    const bool hasH = (hfx >= 0);
    const int hcu = (hfy + 1) * UX + (hfx + 1);
    const int hfi = hfy * FX + hfx;

    // staging sites (loop-invariant global row offsets)
    const int  q0   = tid;
    const int  q1   = tid + NT;
    const bool has2 = (q1 < UP);
    int ro0, ro1 = 0;
    {
        const int ux = q0 % UX, uy = q0 / UX;
        ro0 = wrapN(by + uy - 2) * N + wrapN(bx + ux - 2);
    }
    if (has2) {
        const int ux = q1 % UX, uy = q1 / UX;
        ro1 = wrapN(by + uy - 2) * N + wrapN(bx + ux - 2);
    }

#define STAGE_DIRECT(slot, zw)                                              \
    do {                                                                    \
        const int base_ = (zw) * N2;                                        \
        {  const int g_ = base_ + ro0;                                      \
           su4[slot][q0] = make_float4(u0[g_], u1[g_], u2[g_], Tp[g_]); }   \
        if (has2) {                                                         \
           const int g_ = base_ + ro1;                                      \
           su4[slot][q1] = make_float4(u0[g_], u1[g_], u2[g_], Tp[g_]); }   \
    } while (0)

    // ---- prologue ----
    STAGE_DIRECT(0, wrapN(z0 - 2));   // z0-2
    STAGE_DIRECT(1, wrapN(z0 - 1));   // z0-1
    STAGE_DIRECT(2, z0);              // z0
    __syncthreads();

    float t00m, t01m, t02m, F0m;      // flux(z-1) z-fields
    {
        const Flux fM = flux_eval_at(su4[0], su4[1], su4[2], cu);
        t00m = fM.t00; t01m = fM.t01; t02m = fM.t02; F0m = fM.F0;
    }
    __syncthreads();                   // slot0 reads done
    STAGE_DIRECT(0, z0 + 1);          // slot0 <- z0+1
    __syncthreads();

    float t00c, t01c, t02c, F0c;      // flux(z) z-fields
    float4 rA, rB;                    // own u columns: u(z), u(z+1)
    float4 hA = make_float4(0,0,0,0), hB = make_float4(0,0,0,0);
    {
        const Flux fC = flux_eval_at(su4[1], su4[2], su4[0], cu);
        t00c = fC.t00; t01c = fC.t01; t02c = fC.t02; F0c = fC.F0;
        sfAY[fi] = make_float4(fC.t01, fC.t11, fC.t12, fC.F1);
        sfAX[fi] = make_float4(fC.t02, fC.t12, fC.t22, fC.F2);
        if (hasH) {
            const Flux h = flux_eval_at(su4[1], su4[2], su4[0], hcu);
            sfAY[hfi] = make_float4(h.t01, h.t11, h.t12, h.F1);
            sfAX[hfi] = make_float4(h.t02, h.t12, h.t22, h.F2);
            hA = su4[2][hcu];          // u(z0) halo column
            hB = su4[0][hcu];          // u(z0+1)
        }
        rA = su4[2][cu];               // u(z0)
        rB = su4[0][cu];               // u(z0+1)
    }
    __syncthreads();                   // slots 1,2 reads done; sfA visible
    STAGE_DIRECT(1, z0 + 2);          // slot1 <- z0+2
    STAGE_DIRECT(2, z0 + 3);          // slot2 <- z0+3
    __syncthreads();

    // slots: pA = u(z+1) [xy src for flux z+1], pB = u(z+2), pC = u(z+3)
    float4 *pA = su4[0], *pB = su4[1], *pC = su4[2];

    int idx = z0 * N2 + (by + ty) * N + bx + tx;   // += 2*N2 per iteration

    // ---- main loop: TWO output planes per iteration, 2 lgkm barriers ----
    for (int k = 0; k < NIT; ++k) {
        const int  z    = z0 + 2 * k;
        const bool pref = (k < NIT - 1);

        // 1) prefetch u(z+4), u(z+5) into registers (written post-B1)
        float4 r4a, r4b, r5a, r5b;
        if (pref) {
            const int za = wrapN(z + 4), zb = wrapN(z + 5);
            { const int g = za * N2 + ro0;
              r4a = make_float4(u0[g], u1[g], u2[g], Tp[g]); }
            if (has2) { const int g = za * N2 + ro1;
              r4b = make_float4(u0[g], u1[g], u2[g], Tp[g]); }
            { const int g = zb * N2 + ro0;
              r5a = make_float4(u0[g], u1[g], u2[g], Tp[g]); }
            if (has2) { const int g = zb * N2 + ro1;
              r5b = make_float4(u0[g], u1[g], u2[g], Tp[g]); }
        }

        // 2) pre-B1 LDS reads (everything read before the dead slots rewrite)
        const float4 ayp = sfAY[fi + FX], aym = sfAY[fi - FX];   // flux(z) xy
        const float4 axp = sfAX[fi + 1],  axm = sfAX[fi - 1];
        const float4 oB  = pB[cu];                                // u(z+2) own
        const float4 oC  = pC[cu];                                // u(z+3) own
        const float4 xpa = pA[cu + 1],  xma = pA[cu - 1];         // xy of u(z+1)
        const float4 ypa = pA[cu + UX], yma = pA[cu - UX];
        const float4 xpb = pB[cu + 1],  xmb = pB[cu - 1];         // xy of u(z+2)
        const float4 ypb = pB[cu + UX], ymb = pB[cu - UX];
        float4 hoB, hoC, hxpa, hxma, hypa, hyma, hxpb, hxmb, hypb, hymb;
        if (hasH) {
            hoB  = pB[hcu];       hoC  = pC[hcu];
            hxpa = pA[hcu + 1];   hxma = pA[hcu - 1];
            hypa = pA[hcu + UX];  hyma = pA[hcu - UX];
            hxpb = pB[hcu + 1];   hxmb = pB[hcu - 1];
            hypb = pB[hcu + UX];  hymb = pB[hcu - UX];
        }

        // B1: lgkm-only (LDS reads done before dead-slot/sf overwrites)
        asm volatile("s_waitcnt lgkmcnt(0)\n\ts_barrier" ::: "memory");

        // 3) two independent flux evals (2x ILP in the latency-critical phase)
        const Flux P1 = flux_eval(rA, rB, oB, xpa, xma, ypa, yma);  // flux(z+1)
        const Flux P2 = flux_eval(rB, oB, oC, xpb, xmb, ypb, ymb);  // flux(z+2)
        Flux H1, H2;
        if (hasH) {
            H1 = flux_eval(hA, hB, hoB, hxpa, hxma, hypa, hyma);
            H2 = flux_eval(hB, hoB, hoC, hxpb, hxmb, hypb, hymb);
        }

        // 4) post-B1 writes: sfB <- flux(z+1); sfA <- flux(z+2);
        //    dead u slots <- u(z+4), u(z+5)
        sfBY[fi] = make_float4(P1.t01, P1.t11, P1.t12, P1.F1);
        sfBX[fi] = make_float4(P1.t02, P1.t12, P1.t22, P1.F2);
        sfAY[fi] = make_float4(P2.t01, P2.t11, P2.t12, P2.F1);
        sfAX[fi] = make_float4(P2.t02, P2.t12, P2.t22, P2.F2);
        if (hasH) {
            sfBY[hfi] = make_float4(H1.t01, H1.t11, H1.t12, H1.F1);
            sfBX[hfi] = make_float4(H1.t02, H1.t12, H1.t22, H1.F2);
            sfAY[hfi] = make_float4(H2.t01, H2.t11, H2.t12, H2.F1);
            sfAX[hfi] = make_float4(H2.t02, H2.t12, H2.t22, H2.F2);
        }
        if (pref) {
            pA[q0] = r4a; if (has2) pA[q1] = r4b;   // u(z+4)
            pB[q0] = r5a; if (has2) pB[q1] = r5b;   // u(z+5)
        }

        // 5) output plane z (flux(z) xy from pre-B1 regs; z-part P1 - m)
        const float m0a = (P1.t00 - t00m) + (ayp.x - aym.x) + (axp.x - axm.x);
        const float m1a = (P1.t01 - t01m) + (ayp.y - aym.y) + (axp.y - axm.y);
        const float m2a = (P1.t02 - t02m) + (ayp.z - aym.z) + (axp.z - axm.z);
        const float ena = (P1.F0  - F0m)  + (ayp.w - aym.w) + (axp.w - axm.w);
        __builtin_nontemporal_store(m0a * SCALE2, &out[1 * N3 + idx]);
        __builtin_nontemporal_store(m1a * SCALE2, &out[2 * N3 + idx]);
        __builtin_nontemporal_store(m2a * SCALE2, &out[3 * N3 + idx]);
        __builtin_nontemporal_store(ena * SCALE2, &out[4 * N3 + idx]);

        // B2: lgkm-only (sfB/sfA/u writes visible)
        asm volatile("s_waitcnt lgkmcnt(0)\n\ts_barrier" ::: "memory");

        // 6) output plane z+1 (flux(z+1) xy from sfB; z-part P2 - c)
        const float4 byp = sfBY[fi + FX], bym = sfBY[fi - FX];
        const float4 bxp = sfBX[fi + 1],  bxm = sfBX[fi - 1];
        const float m0b = (P2.t00 - t00c) + (byp.x - bym.x) + (bxp.x - bxm.x);
        const float m1b = (P2.t01 - t01c) + (byp.y - bym.y) + (bxp.y - bxm.y);
        const float m2b = (P2.t02 - t02c) + (byp.z - bym.z) + (bxp.z - bxm.z);
        const float enb = (P2.F0  - F0c)  + (byp.w - bym.w) + (bxp.w - bxm.w);
        const int idx1 = idx + N2;
        __builtin_nontemporal_store(m0b * SCALE2, &out[1 * N3 + idx1]);
        __builtin_nontemporal_store(m1b * SCALE2, &out[2 * N3 + idx1]);
        __builtin_nontemporal_store(m2b * SCALE2, &out[3 * N3 + idx1]);
        __builtin_nontemporal_store(enb * SCALE2, &out[4 * N3 + idx1]);

        // 7) rotate pipeline state
        t00m = P1.t00; t01m = P1.t01; t02m = P1.t02; F0m = P1.F0;
        t00c = P2.t00; t01c = P2.t01; t02c = P2.t02; F0c = P2.F0;
        rA = oB; rB = oC;
        if (hasH) { hA = hoB; hB = hoC; }
        float4* t = pA; pA = pC; pC = pB; pB = t;   // (z+3, z+4, z+5)
        idx += 2 * N2;
    }
#undef STAGE_DIRECT
}

extern "C" void kernel_launch(void* const* d_in, const int* in_sizes, int n_in,
                              void* d_out, int out_size, void* d_ws, size_t ws_size,
                              hipStream_t stream)
{
    const float* u   = (const float*)d_in[0];   // [3, N, N, N]
    const float* T   = (const float*)d_in[1];   // [N, N, N]
    float*       out = (float*)d_out;           // [5, N, N, N]

    // mass channel is identically zero — write it with a memset, not 7M stores
    hipMemsetAsync(out, 0, (size_t)N3 * sizeof(float), stream);

    hipLaunchKernelGGL(diffusion_zmarch2_kernel, dim3(NBLK), dim3(NT), 0, stream,
                       u, T, out);
}

// Round 17
// 101.055 us; speedup vs baseline: 1.9085x; 1.9085x over previous
//
#include <hip/hip_runtime.h>

#define N  192
#define N2 (N * N)
#define N3 (N * N * N)

// Block: 32x8 (x,y) tile marching ZC planes in z (axis0).  (R8 geometry)
// R15/R17: best-known configuration — 5 blocks/CU, register z-pipeline,
// direction-packed single-buffer sf, lgkm-only barriers (no vmcnt drain),
// deferred LDS writes, XCD-swizzled grid, memset'd mass channel.
#define TX 32
#define TY 8
#define NT 256
#define ZC 12
#define GX (N / TX)           // 6
#define GY (N / TY)           // 24
#define GZ (N / ZC)           // 16
#define NBLK (GX * GY * GZ)   // 2304 (divisible by 8 XCDs)
#define UX (TX + 4)           // 36  (u/T halo +-2)
#define UY (TY + 4)           // 12
#define UP (UX * UY)          // 432
#define FX (TX + 2)           // 34  (flux halo +-1)
#define FY (TY + 2)           // 10
#define FP (FX * FY)          // 340

static constexpr float INV2DX     = (float)N / 2.0f;   // 96
static constexpr float SCALE2     = INV2DX * INV2DX;   // 9216 (exact)
static constexpr float MU_REF_F   = 1.8e-5f;
static constexpr float CP_OVER_PR = 1005.0f / 0.72f;
static constexpr float TWO_THIRDS = 2.0f / 3.0f;

__device__ __forceinline__ int wrapN(int a) {  // valid for a in [-N, 2N)
    if (a < 0)  a += N;
    if (a >= N) a -= N;
    return a;
}

struct Flux { float t00, t01, t02, t11, t12, t22, F0, F1, F2; };

// Flux at a site given its own column {zm, cc, zp} in registers; the 4
// xy-neighbors come from LDS (ds_read_b128 x4). No 1/(2dx) factor — the
// single INV2DX^2 is applied at the output store.
__device__ __forceinline__ Flux flux_eval_reg(const float4 zm, const float4 cc,
                                              const float4 zp,
                                              const float4* __restrict__ uC, int c)
{
    const float4 xp = uC[c + 1],  xm = uC[c - 1];
    const float4 yp = uC[c + UX], ym = uC[c - UX];

    const float d00 = zp.x - zm.x;
    const float d01 = yp.x - ym.x;
    const float d02 = xp.x - xm.x;
    const float d10 = zp.y - zm.y;
    const float d11 = yp.y - ym.y;
    const float d12 = xp.y - xm.y;
    const float d20 = zp.z - zm.z;
    const float d21 = yp.z - ym.z;
    const float d22 = xp.z - xm.z;
    const float dT0 = zp.w - zm.w;
    const float dT1 = yp.w - ym.w;
    const float dT2 = xp.w - xm.w;

    const float mu   = MU_REF_F * __powf(cc.w, 0.7f);
    const float mu2  = mu + mu;
    const float divu = d00 + d11 + d22;
    const float lam  = -TWO_THIRDS * mu * divu;

    Flux f;
    f.t00 = mu2 * d00 + lam;
    f.t11 = mu2 * d11 + lam;
    f.t22 = mu2 * d22 + lam;
    f.t01 = mu * (d01 + d10);
    f.t02 = mu * (d02 + d20);
    f.t12 = mu * (d12 + d21);
    const float kc = mu * CP_OVER_PR;
    f.F0 = kc * dT0 + f.t00 * cc.x + f.t01 * cc.y + f.t02 * cc.z;
    f.F1 = kc * dT1 + f.t01 * cc.x + f.t11 * cc.y + f.t12 * cc.z;
    f.F2 = kc * dT2 + f.t02 * cc.x + f.t12 * cc.y + f.t22 * cc.z;
    return f;
}

// Prologue-only variant: whole column from LDS.
__device__ __forceinline__ Flux flux_eval_lds(const float4* __restrict__ uM,
                                              const float4* __restrict__ uC,
                                              const float4* __restrict__ uP, int c)
{
    return flux_eval_reg(uM[c], uC[c], uP[c], uC, c);
}

// sf packing by derivative direction:
//   sfY[fi] = {t01, t11, t12, F1}  (read at fi +- FX for the y-derivative)
//   sfX[fi] = {t02, t12, t22, F2}  (read at fi +- 1  for the x-derivative)
__device__ __forceinline__ void sf_store(float4* __restrict__ sY, float4* __restrict__ sX,
                                         int fi, const Flux& f)
{
    sY[fi] = make_float4(f.t01, f.t11, f.t12, f.F1);
    sX[fi] = make_float4(f.t02, f.t12, f.t22, f.F2);
}

__global__ __launch_bounds__(NT)
void diffusion_zmarch_kernel(const float* __restrict__ u,
                             const float* __restrict__ Tp,
                             float* __restrict__ out)
{
    __shared__ float4 su4[3][UP];     // 3 rolling packed u/T planes (20.25 KB)
    __shared__ float4 sfY[FP];        // flux y-fields, SINGLE buffer (5.3 KB)
    __shared__ float4 sfX[FP];        // flux x-fields, SINGLE buffer (5.3 KB)
    // total 30.9 KB -> 5 blocks/CU

    // ---- bijective XCD swizzle on the flat block id (NBLK % 8 == 0) ----
    const int id  = (int)blockIdx.x;
    const int nid = (id & 7) * (NBLK / 8) + (id >> 3);
    const int bzB = nid / (GX * GY);
    const int rem = nid % (GX * GY);
    const int bx  = (rem % GX) * TX;
    const int by  = (rem / GX) * TY;
    const int z0  = bzB * ZC;

    const int tx  = threadIdx.x & (TX - 1);
    const int ty  = threadIdx.x >> 5;
    const int tid = (int)threadIdx.x;

    const float* __restrict__ u0 = u;
    const float* __restrict__ u1 = u + N3;
    const float* __restrict__ u2 = u + 2 * N3;

    const int cu = (ty + 2) * UX + (tx + 2);   // interior u-site
    const int fi = (ty + 1) * FX + (tx + 1);   // interior flux-site

    // halo flux site for tid < 80 (corners excluded — never read)
    int hfx = -1, hfy = -1;
    if (tid < TX)                 { hfy = 0;      hfx = 1 + tid; }
    else if (tid < 2 * TX)        { hfy = FY - 1; hfx = 1 + tid - TX; }
    else if (tid < 2 * TX + TY)   { hfx = 0;      hfy = 1 + tid - 2 * TX; }
    else if (tid < 2 * (TX + TY)) { hfx = FX - 1; hfy = 1 + tid - 2 * TX - TY; }
    const bool hasH = (hfx >= 0);
    const int hcu = (hfy + 1) * UX + (hfx + 1);
    const int hfi = hfy * FX + hfx;

    // staging sites for this thread (loop-invariant global row offsets)
    const int  q0   = tid;
    const int  q1   = tid + NT;
    const bool has2 = (q1 < UP);
    int ro0, ro1 = 0;
    {
        const int ux = q0 % UX, uy = q0 / UX;
        ro0 = wrapN(by + uy - 2) * N + wrapN(bx + ux - 2);
    }
    if (has2) {
        const int ux = q1 % UX, uy = q1 / UX;
        ro1 = wrapN(by + uy - 2) * N + wrapN(bx + ux - 2);
    }

#define STAGE_DIRECT(slot, zw)                                              \
    do {                                                                    \
        const int base_ = (zw) * N2;                                        \
        {  const int g_ = base_ + ro0;                                      \
           su4[slot][q0] = make_float4(u0[g_], u1[g_], u2[g_], Tp[g_]); }   \
        if (has2) {                                                         \
           const int g_ = base_ + ro1;                                      \
           su4[slot][q1] = make_float4(u0[g_], u1[g_], u2[g_], Tp[g_]); }   \
    } while (0)

    // ---- prologue ----
    STAGE_DIRECT(0, wrapN(z0 - 2));   // z0-2
    STAGE_DIRECT(1, wrapN(z0 - 1));   // z0-1
    STAGE_DIRECT(2, z0);              // z0
    __syncthreads();

    float t00m, t01m, t02m, F0m;      // flux(z-1) z-fields
    {
        const Flux fM = flux_eval_lds(su4[0], su4[1], su4[2], cu);
        t00m = fM.t00; t01m = fM.t01; t02m = fM.t02; F0m = fM.F0;
    }
    __syncthreads();                   // slot0 reads done
    STAGE_DIRECT(0, z0 + 1);          // slot0 <- z0+1
    __syncthreads();

    float t00c, t01c, t02c, F0c;      // flux(z) z-fields
    {
        const Flux fC = flux_eval_lds(su4[1], su4[2], su4[0], cu);
        t00c = fC.t00; t01c = fC.t01; t02c = fC.t02; F0c = fC.F0;
        sf_store(sfY, sfX, fi, fC);
        if (hasH) {
            const Flux h = flux_eval_lds(su4[1], su4[2], su4[0], hcu);
            sf_store(sfY, sfX, hfi, h);
        }
    }
    __syncthreads();                   // slot1 reads done, sf visible
    STAGE_DIRECT(1, z0 + 2);          // slot1 <- z0+2
    __syncthreads();

    // register z-pipeline: own-column values for the flux plane
    float4 rzm = su4[2][cu];          // u(z0)
    float4 rcc = su4[0][cu];          // u(z0+1)
    float4 hzm, hcc;
    if (hasH) { hzm = su4[2][hcu]; hcc = su4[0][hcu]; }

    // slots: pC = z+1 (xy-neighbor source), pP = z+2 (own-read), pW = overwrite
    float4 *pC = su4[0], *pP = su4[1], *pW = su4[2];

    int idx = z0 * N2 + (by + ty) * N + bx + tx;   // output index, += N2/iter
    int zw  = z0 + 3; if (zw >= N) zw -= N;        // prefetch plane, wrapped

    // ---- main loop: one output plane per iteration ----
    for (int it = 0; it < ZC; ++it) {
        // 1) issue next plane's global loads early (consumed at step 6)
        const bool pref = (it <= ZC - 2);
        float4 r0, r1;
        if (pref) {
            const int base_ = zw * N2;
            { const int g_ = base_ + ro0;
              r0 = make_float4(u0[g_], u1[g_], u2[g_], Tp[g_]); }
            if (has2) {
              const int g_ = base_ + ro1;
              r1 = make_float4(u0[g_], u1[g_], u2[g_], Tp[g_]); }
        }

        // 2) pre-barrier LDS reads: sf(z) xy-neighbors + own u-column at z+2
        const float4 yp = sfY[fi + FX], ym = sfY[fi - FX];
        const float4 xp = sfX[fi + 1],  xm = sfX[fi - 1];
        const float4 own = pP[cu];
        float4 hown;
        if (hasH) hown = pP[hcu];

        // 3) mid-barrier: orders LDS reads vs the sf overwrites below,
        //    WITHOUT draining vmcnt — the prefetch globals stay in flight.
        asm volatile("s_waitcnt lgkmcnt(0)\n\ts_barrier" ::: "memory");

        // 4) flux(z+1): own column from regs; xy from pC (read-only this iter)
        const Flux fp_ = flux_eval_reg(rzm, rcc, own, pC, cu);
        Flux h;
        if (hasH) h = flux_eval_reg(hzm, hcc, hown, pC, hcu);

        // 5) divergence for output plane z (values only; stores deferred)
        const float m0 = (fp_.t00 - t00m) + (yp.x - ym.x) + (xp.x - xm.x);
        const float m1 = (fp_.t01 - t01m) + (yp.y - ym.y) + (xp.y - xm.y);
        const float m2 = (fp_.t02 - t02m) + (yp.z - ym.z) + (xp.z - xm.z);
        const float en = (fp_.F0  - F0m)  + (yp.w - ym.w) + (xp.w - xm.w);

        // 6) LDS writes first: sf <- flux(z+1); dead u-slot <- u(z+3).
        sf_store(sfY, sfX, fi, fp_);
        if (hasH) sf_store(sfY, sfX, hfi, h);
        if (pref) { pW[q0] = r0; if (has2) pW[q1] = r1; }

        // 7) global stores AFTER the LDS writes — they retire across the
        //    barrier below (no vmcnt drain anywhere in the loop).
        __builtin_nontemporal_store(m0 * SCALE2, &out[1 * N3 + idx]);
        __builtin_nontemporal_store(m1 * SCALE2, &out[2 * N3 + idx]);
        __builtin_nontemporal_store(m2 * SCALE2, &out[3 * N3 + idx]);
        __builtin_nontemporal_store(en * SCALE2, &out[4 * N3 + idx]);

        // 8) end barrier: LDS-only ordering (sf/pW writes vs next-iter reads)
        asm volatile("s_waitcnt lgkmcnt(0)\n\ts_barrier" ::: "memory");

        // 9) rotate pipeline state (registers + slot pointers)
        t00m = t00c; t01m = t01c; t02m = t02c; F0m = F0c;
        t00c = fp_.t00; t01c = fp_.t01; t02c = fp_.t02; F0c = fp_.F0;
        rzm = rcc; rcc = own;
        if (hasH) { hzm = hcc; hcc = hown; }
        float4* t = pC; pC = pP; pP = pW; pW = t;
        idx += N2;
        if (++zw >= N) zw = 0;
    }
#undef STAGE_DIRECT
}

extern "C" void kernel_launch(void* const* d_in, const int* in_sizes, int n_in,
                              void* d_out, int out_size, void* d_ws, size_t ws_size,
                              hipStream_t stream)
{
    const float* u   = (const float*)d_in[0];   // [3, N, N, N]
    const float* T   = (const float*)d_in[1];   // [N, N, N]
    float*       out = (float*)d_out;           // [5, N, N, N]

    // mass channel is identically zero — write it with a memset, not 7M stores
    hipMemsetAsync(out, 0, (size_t)N3 * sizeof(float), stream);

    hipLaunchKernelGGL(diffusion_zmarch_kernel, dim3(NBLK), dim3(NT), 0, stream,
                       u, T, out);
}